// Round 7
// baseline (388.152 us; speedup 1.0000x reference)
//
#include <hip/hip_runtime.h>
#include <math.h>

#define BB 8
#define CCH 256
#define QQ 4
#define NN 1600          // H*W
#define BQN 32           // B*Q
#define SP 51200         // BQN*NN
#define EPSF 1e-5f

typedef __attribute__((ext_vector_type(8))) short bf16x8;  // 8 bf16 (4 VGPRs)
typedef __attribute__((ext_vector_type(4))) float f32x4;

static __device__ inline ushort f2bf(float f) {
  union { float f; unsigned u; } v; v.f = f;
  return (ushort)((v.u + 0x7fffu + ((v.u >> 16) & 1u)) >> 16);  // RNE
}

// ---------------- fake-quant weights (-> bf16, QKV fused) + gamma + bias fuse ----------------
__global__ void quant_weights_kernel(const float* Wq, const float* Wk,
                                     const float* Wv, const float* Wp,
                                     const float* gamma,
                                     const float* bq, const float* bk, const float* bv,
                                     ushort* wqkv, ushort* wp,
                                     float* gq, float* bqkv) {
  __shared__ float red[256];
  int blk = blockIdx.x;
  int tid = threadIdx.x;
  if (blk < 1024) {
    int mat = blk >> 8;
    int row = blk & 255;
    const float* W = (mat == 0) ? Wq : (mat == 1) ? Wk : (mat == 2) ? Wv : Wp;
    ushort* O      = (mat < 3) ? (wqkv + mat * 65536) : wp;
    float w = W[row * 256 + tid];
    red[tid] = fabsf(w);
    __syncthreads();
    for (int s = 128; s > 0; s >>= 1) {
      if (tid < s) red[tid] = fmaxf(red[tid], red[tid + s]);
      __syncthreads();
    }
    float s = red[0] / 127.0f + 1e-8f;
    float q = fminf(fmaxf(rintf(w / s), -127.0f), 127.0f) * s;
    O[row * 256 + tid] = f2bf(q);
  } else {
    float g = gamma[tid];
    red[tid] = fabsf(g);
    __syncthreads();
    for (int s = 128; s > 0; s >>= 1) {
      if (tid < s) red[tid] = fmaxf(red[tid], red[tid + s]);
      __syncthreads();
    }
    float s = red[0] / 127.0f + 1e-8f;
    float q = fminf(fmaxf(rintf(g / s), -127.0f), 127.0f) * s;
    gq[tid] = q;
    bqkv[tid] = bq[tid];
    bqkv[256 + tid] = bk[tid];
    bqkv[512 + tid] = bv[tid];
  }
}

// ---------------- transpose x: [b][c][q][n] fp32 -> xT[s=bqi*NN+n][c] bf16 ----------------
__global__ __launch_bounds__(256)
void transpose_x_kernel(const float* __restrict__ x, ushort* __restrict__ xT) {
  int bqi = blockIdx.z, b = bqi >> 2, q = bqi & 3;
  int s0 = blockIdx.x * 64, c0 = blockIdx.y * 64;
  __shared__ ushort lT[64 * 66];
  int tid = threadIdx.x;
  int c = tid >> 2, nch = (tid & 3) * 16;
  const float* xp = x + ((size_t)(b * CCH + c0 + c) * QQ + q) * NN + s0 + nch;
#pragma unroll
  for (int j = 0; j < 4; j++) {
    float4 f = ((const float4*)xp)[j];
    lT[c * 66 + nch + j * 4 + 0] = f2bf(f.x);
    lT[c * 66 + nch + j * 4 + 1] = f2bf(f.y);
    lT[c * 66 + nch + j * 4 + 2] = f2bf(f.z);
    lT[c * 66 + nch + j * 4 + 3] = f2bf(f.w);
  }
  __syncthreads();
  int n = tid >> 2, cch = (tid & 3) * 16;
  union { ushort u[16]; int4 v[2]; } o;
#pragma unroll
  for (int i = 0; i < 16; i++) o.u[i] = lT[(cch + i) * 66 + n];
  ushort* dst = xT + (size_t)(bqi * NN + s0 + n) * CCH + c0 + cch;
  *(int4*)dst = o.v[0];
  *((int4*)dst + 1) = o.v[1];
}

// ---------------- direct-register bf16 MFMA GEMM: C[M][N] = A[M][K] * B[N][K]^T ----------------
// No LDS / no __syncthreads in the K-loop: each wave loads its MFMA fragments
// straight global->VGPR (global_load_dwordx4; the 4 quad-chunks of a row are
// contiguous 64 B, fully-used cache lines). Compiler pipelines iterations with
// per-wave fine-grained vmcnt (#pragma unroll 2 bounds VGPR). Redundant A/B
// fetches across waves/blocks hit L1/L2 (QKV keeps the XCD swizzle for B).
// EPI 2: f32 [m][n]*scale      3: bf16 [n][m]
//     4: f32 strided [b][o][q][n]+bias[m], + per-row stats partials
//     5: fused QKV: mat0/1 row-major bf16 + bias; mat2 transposed bf16 + bias
template<int EPI, int SWAP, int SPLITK, int SWIZ>
__global__ __launch_bounds__(256)
void gemm128(const ushort* __restrict__ A, int lda, long sA,
             const ushort* __restrict__ B, int ldb, long sB,
             void* __restrict__ Cv, int ldc, long sC,
             const float* __restrict__ bias, float scale, int K, int Nlim,
             float* __restrict__ part)
{
  __shared__ float lC[4 * 16 * 68];   // epilogue staging only (17.4 KB)
  __shared__ float psS[256], psS2[256];

  int z = blockIdx.z;
  int mBase, nBase;
  if (SWIZ) {
    int blk = blockIdx.x;
    int xcd = blk & 7, l = blk >> 3;
    mBase = (l % 6) * 128;
    nBase = ((l / 6) * 8 + xcd) * 128;
  } else if (SWAP) { mBase = blockIdx.x * 128; nBase = blockIdx.y * 128; }
  else             { mBase = blockIdx.y * 128; nBase = blockIdx.x * 128; }
  int tid = threadIdx.x, wave = tid >> 6, lane = tid & 63;
  int wm = wave >> 1, wn = wave & 1;
  int col = lane & 15, quad = lane >> 4;

  const ushort* Az;
  const ushort* Bz;
  int Kc = K;
  if (SPLITK) {
    int bqi = z & 31, chunk = z >> 5;
    int kbase = chunk * 416;
    Kc = 1600 - kbase; if (Kc > 416) Kc = 416;
    Az = A + (size_t)bqi * sA + kbase;
    Bz = B + (size_t)bqi * sB + kbase;
  } else {
    Az = A + (size_t)z * sA;
    Bz = B + (size_t)z * sB;
  }
  // per-lane fragment pointers: A rows (always in-bounds), B rows (clamped)
  const ushort* ap = Az + (size_t)(mBase + wm * 64 + col) * lda + quad * 8;
  const ushort* bp[4];
#pragma unroll
  for (int j = 0; j < 4; j++) {
    int r = nBase + wn * 64 + j * 16 + col;
    r = r < Nlim ? r : Nlim - 1;
    bp[j] = Bz + (size_t)r * ldb + quad * 8;
  }

  f32x4 acc[4][4];
#pragma unroll
  for (int i = 0; i < 4; i++)
#pragma unroll
    for (int j = 0; j < 4; j++) acc[i][j] = (f32x4){0.f, 0.f, 0.f, 0.f};

#pragma unroll 2
  for (int kt = 0; kt < Kc; kt += 32) {
    bf16x8 af[4], bfr[4];
#pragma unroll
    for (int i = 0; i < 4; i++)
      af[i] = *(const bf16x8*)(ap + (size_t)(i * 16) * lda + kt);
#pragma unroll
    for (int j = 0; j < 4; j++)
      bfr[j] = *(const bf16x8*)(bp[j] + kt);
#pragma unroll
    for (int i = 0; i < 4; i++)
#pragma unroll
      for (int j = 0; j < 4; j++)
        acc[i][j] = __builtin_amdgcn_mfma_f32_16x16x32_bf16(af[i], bfr[j], acc[i][j], 0, 0, 0);
  }

  // epilogue: per-wave private LDS staging
  float* lCw = lC + wave * 16 * 68;
  int mW = mBase + wm * 64;
  int nW = nBase + wn * 64;
#pragma unroll
  for (int i = 0; i < 4; i++) {
#pragma unroll
    for (int j = 0; j < 4; j++)
#pragma unroll
      for (int r = 0; r < 4; r++)
        lCw[(quad * 4 + r) * 68 + j * 16 + col] = acc[i][j][r];

    int mrow0 = mW + i * 16;
    if (EPI == 2) {
      int rr = lane & 15, cc = lane >> 4;
      float* C = (float*)Cv + (size_t)z * sC + (size_t)(mrow0 + rr) * ldc + nW + cc * 16;
#pragma unroll
      for (int v = 0; v < 4; v++) {
        float4 f;
        f.x = lCw[rr * 68 + cc * 16 + v * 4 + 0] * scale;
        f.y = lCw[rr * 68 + cc * 16 + v * 4 + 1] * scale;
        f.z = lCw[rr * 68 + cc * 16 + v * 4 + 2] * scale;
        f.w = lCw[rr * 68 + cc * 16 + v * 4 + 3] * scale;
        *(float4*)(C + v * 4) = f;
      }
    } else if (EPI == 3) {
      int n = nW + lane;
      if (n < Nlim) {
        union { ushort u[16]; int4 v[2]; } o;
#pragma unroll
        for (int t = 0; t < 16; t++) o.u[t] = f2bf(lCw[t * 68 + lane]);
        ushort* C = (ushort*)Cv + (size_t)z * sC + (size_t)n * ldc + mrow0;
        *(int4*)C = o.v[0];
        *((int4*)C + 1) = o.v[1];
      }
    } else if (EPI == 4) {
      int rr = lane & 15, cc = lane >> 4;
      int s0g = nW + cc * 16;
      int bqi = s0g / 1600, n0 = s0g - bqi * 1600;
      int b = bqi >> 2, q = bqi & 3;
      float bi = bias[mrow0 + rr];
      float* C = (float*)Cv + (size_t)b * (CCH * QQ * NN)
               + (size_t)(mrow0 + rr) * (QQ * NN) + (size_t)q * NN + n0;
      float ls = 0.f, ls2 = 0.f;
#pragma unroll
      for (int v = 0; v < 4; v++) {
        float4 f;
        f.x = lCw[rr * 68 + cc * 16 + v * 4 + 0] + bi;
        f.y = lCw[rr * 68 + cc * 16 + v * 4 + 1] + bi;
        f.z = lCw[rr * 68 + cc * 16 + v * 4 + 2] + bi;
        f.w = lCw[rr * 68 + cc * 16 + v * 4 + 3] + bi;
        *(float4*)(C + v * 4) = f;
        ls  += f.x + f.y + f.z + f.w;
        ls2 += f.x * f.x + f.y * f.y + f.z * f.z + f.w * f.w;
      }
      ls  += __shfl_down(ls, 32);  ls  += __shfl_down(ls, 16);
      ls2 += __shfl_down(ls2, 32); ls2 += __shfl_down(ls2, 16);
      if (lane < 16) {
        // two wn-waves write disjoint halves summed later via both columns
        psS[(wm * 64 + i * 16 + lane)] = (wn == 0) ? ls : psS[(wm * 64 + i * 16 + lane)];
        // NOTE: replaced below by 2-column scheme
      }
      if (lane < 16) {
        psS2[(wm * 64 + i * 16 + lane)] = 0.f;  // placeholder (overwritten)
      }
      // store into 2-column layout at tail of lC region is unsafe; use dedicated:
      if (lane < 16) {
        ((float*)psS)[(wm * 64 + i * 16 + lane)] = ls;   // wn==1 overwrites wn==0!
      }
      // -- the above race is resolved by the wn-split arrays below --
      if (lane < 16) {
        if (wn == 0) psS[wm * 64 + i * 16 + lane] = ls;
        else         psS2[wm * 64 + i * 16 + lane] = ls;
      }
    } else {  // EPI 5: fused QKV
      int mat = mrow0 >> 8;   // block-uniform (tile never crosses a 256 boundary)
      if (mat < 2) {
        int rr = lane & 15, cc = lane >> 4;
        int g = mrow0 + rr;
        float bi = bias[g];
        union { ushort u[16]; int4 v[2]; } o;
#pragma unroll
        for (int t = 0; t < 16; t++) o.u[t] = f2bf(lCw[rr * 68 + cc * 16 + t] + bi);
        ushort* C = (ushort*)Cv + (size_t)mat * 256 * ldc
                  + (size_t)(g & 255) * ldc + nW + cc * 16;
        *(int4*)C = o.v[0];
        *((int4*)C + 1) = o.v[1];
      } else {
        int n = nW + lane;
        union { ushort u[16]; int4 v[2]; } o;
#pragma unroll
        for (int t = 0; t < 16; t++)
          o.u[t] = f2bf(lCw[t * 68 + lane] + bias[mrow0 + t]);
        ushort* C = (ushort*)Cv + (size_t)2 * 256 * ldc + (size_t)n * 256 + (mrow0 & 255);
        *(int4*)C = o.v[0];
        *((int4*)C + 1) = o.v[1];
      }
    }
  }
  if (EPI == 4) {
    // psS: sum over columns split by wn (psS=wn0 sums, psS2 holds wn1 sums of ls;
    // squared sums carried in registers via second pass)
    __syncthreads();
    if (tid < 128) {
      float s = psS[tid] + psS2[tid];
      int xt = blockIdx.x;
      part[(size_t)xt * 256 + mBase + tid] = s;
    }
    __syncthreads();
  }
  if (EPI == 4) {
    // second pass for squared sums: recompute from lC is impossible (overwritten
    // per-i); instead each wave kept ls2 only transiently. Redo via accumulators:
    // recompute sums-of-squares directly from acc registers (bias included).
    int rr2 = lane & 15;
    float bi = bias[mW + 0];  // placeholder to keep signature; real calc below
    (void)bi; (void)rr2;
    float s2w[4];
#pragma unroll
    for (int i = 0; i < 4; i++) {
      float bii = bias[mW + i * 16 + quad * 4];
      (void)bii;
      s2w[i] = 0.f;
    }
    // accumulate per output row: row = i*16 + quad*4 + r, col j*16+col
#pragma unroll
    for (int i = 0; i < 4; i++) {
#pragma unroll
      for (int r = 0; r < 4; r++) {
        int row = i * 16 + quad * 4 + r;
        float bii = bias[mW + row];
        float s2 = 0.f;
#pragma unroll
        for (int j = 0; j < 4; j++) {
          float f = acc[i][j][r] + bii;
          s2 += f * f;
        }
        // reduce across the 16 col-lanes sharing this row (lanes with same quad)
        // lanes 0..15 of each quad group: use shfl_xor over low 4 bits
#pragma unroll
        for (int d = 1; d < 16; d <<= 1) s2 += __shfl_xor(s2, d);
        if (col == 0) {
          if (wn == 0) psS[wm * 64 + row] = s2;
          else         psS2[wm * 64 + row] = s2;
        }
      }
    }
    __syncthreads();
    if (tid < 128) {
      float s2 = psS[tid] + psS2[tid];
      int xt = blockIdx.x;
      part[400 * 256 + (size_t)xt * 256 + mBase + tid] = s2;
    }
  }
}

// ---------------- softmax: sum 4 split-K partials, *0.125, softmax, -> bf16 P ----------------
__global__ void softmax_kernel(const float* __restrict__ Sp, ushort* __restrict__ P) {
  int bi = blockIdx.x;               // 0..8191
  int bqi = bi >> 8, r = bi & 255;
  int tid = threadIdx.x;
  size_t off = (size_t)bqi * 65536 + (size_t)r * 256 + tid;
  const size_t cs = (size_t)32 * 65536;
  float v = 0.125f * (Sp[off] + Sp[off + cs] + Sp[off + 2 * cs] + Sp[off + 3 * cs]);
  __shared__ float red[256];
  red[tid] = v;
  __syncthreads();
  for (int s = 128; s > 0; s >>= 1) {
    if (tid < s) red[tid] = fmaxf(red[tid], red[tid + s]);
    __syncthreads();
  }
  float m = red[0];
  __syncthreads();
  float e = expf(v - m);
  red[tid] = e;
  __syncthreads();
  for (int s = 128; s > 0; s >>= 1) {
    if (tid < s) red[tid] += red[tid + s];
    __syncthreads();
  }
  P[off] = f2bf(e / red[0]);
}

// ---------------- stats finalize: reduce 400 partials per channel ----------------
__global__ void stats2_kernel(const float* __restrict__ part, float* __restrict__ st) {
  int o = blockIdx.x;
  int tid = threadIdx.x;
  float s = 0.f, s2 = 0.f;
  for (int x = tid; x < 400; x += 256) {
    s  += part[(size_t)x * 256 + o];
    s2 += part[400 * 256 + (size_t)x * 256 + o];
  }
  __shared__ float rs[256], rs2[256];
  rs[tid] = s; rs2[tid] = s2;
  __syncthreads();
  for (int t = 128; t > 0; t >>= 1) {
    if (tid < t) { rs[tid] += rs[tid + t]; rs2[tid] += rs2[tid + t]; }
    __syncthreads();
  }
  if (tid == 0) {
    float inv = 1.0f / (float)(BQN * NN);
    float mean = rs[0] * inv;
    float var = rs2[0] * inv - mean * mean;
    st[o] = mean;
    st[CCH + o] = var;
  }
}

// ---------------- batch-norm apply (float4) ----------------
__global__ __launch_bounds__(256)
void bn_kernel(float* __restrict__ out, const float* __restrict__ st,
               const float* __restrict__ gq, const float* __restrict__ beta) {
  size_t i4 = (size_t)blockIdx.x * 256 + threadIdx.x;  // 3276800 float4s exactly
  int o = (int)((i4 / 1600) & 255);
  float mean = st[o];
  float g = rsqrtf(st[CCH + o] + EPSF) * gq[o];
  float be = beta[o];
  float4 f = ((const float4*)out)[i4];
  f.x = (f.x - mean) * g + be;
  f.y = (f.y - mean) * g + be;
  f.z = (f.z - mean) * g + be;
  f.w = (f.w - mean) * g + be;
  ((float4*)out)[i4] = f;
}

extern "C" void kernel_launch(void* const* d_in, const int* in_sizes, int n_in,
                              void* d_out, int out_size, void* d_ws, size_t ws_size,
                              hipStream_t stream) {
  const float* x     = (const float*)d_in[0];
  const float* Wq    = (const float*)d_in[1];
  const float* bq    = (const float*)d_in[2];
  const float* Wk    = (const float*)d_in[3];
  const float* bk    = (const float*)d_in[4];
  const float* Wv    = (const float*)d_in[5];
  const float* bv    = (const float*)d_in[6];
  const float* Wp    = (const float*)d_in[7];
  const float* bp    = (const float*)d_in[8];
  const float* gamma = (const float*)d_in[9];
  const float* beta  = (const float*)d_in[10];
  float* out = (float*)d_out;

  // ws layout (Sp overlays dead xT)
  ushort* h    = (ushort*)d_ws;
  ushort* wqkv = h;                          // 768*256 = 196608
  ushort* wph  = wqkv + 196608;              // 65536
  ushort* qkv  = wph + 65536;                // Yq|Yk|Vt : 3 * 256*SP
  ushort* Yq   = qkv;
  ushort* Yk   = qkv + (size_t)256 * SP;
  ushort* Vt   = qkv + (size_t)2 * 256 * SP;
  ushort* Ot   = qkv + (size_t)3 * 256 * SP; // [SP][256]
  ushort* P    = Ot + (size_t)SP * CCH;      // [BQN][256][256] bf16
  ushort* xT   = P + (size_t)BQN * CCH * CCH; // [SP][256] bf16 (dead after QKV gemm)
  float*  Sp   = (float*)xT;                 // [4][BQN][256][256] fp32 overlays xT+
  float*  gq   = Sp + (size_t)4 * BQN * CCH * CCH;
  float*  st   = gq + 256;                   // 512
  float*  part = st + 512;                   // 2*400*256
  float*  bqkv = part + 2 * 400 * 256;       // 768

  quant_weights_kernel<<<1025, 256, 0, stream>>>(Wq, Wk, Wv, Wp, gamma, bq, bk, bv,
                                                 wqkv, wph, gq, bqkv);
  transpose_x_kernel<<<dim3(NN / 64, CCH / 64, BQN), 256, 0, stream>>>(x, xT);

  // fused QKV: [768]x[SP] = wqkv * xT^T ; Q,K row-major, V transposed.
  // XCD-swizzled 1-D grid: 6 m-tiles of each n-tile on one XCD (L2 reuse).
  gemm128<5, 0, 0, 1><<<2400, 256, 0, stream>>>(
      wqkv, 256, 0, xT, 256, 0, qkv, SP, 0, bqkv, 1.f, 256, SP, nullptr);
  // scores split-K=4: Sp[chunk*32+bqi][c][d] = Q[c][:].K[d][:] over k-chunk
  gemm128<2, 0, 1, 0><<<dim3(2, 2, 128), 256, 0, stream>>>(
      Yq, SP, 1600, Yk, SP, 1600, Sp, CCH, 65536, nullptr, 1.f, 416, CCH, nullptr);
  softmax_kernel<<<BQN * CCH, 256, 0, stream>>>(Sp, P);
  // O = P * V -> Ot[s][c]
  gemm128<3, 0, 0, 0><<<dim3((NN + 127) / 128, 2, BQN), 256, 0, stream>>>(
      P, 256, 65536, Vt, 256, (long)NN * CCH, Ot, 256, (long)NN * CCH,
      nullptr, 1.f, 256, NN, nullptr);
  // out = Wp * Ot^T -> out[b][o][q][n] fp32 + bias, + stats partials
  gemm128<4, 0, 0, 0><<<dim3(SP / 128, 2, 1), 256, 0, stream>>>(
      wph, 256, 0, Ot, 256, 0, out, 0, 0, bp, 1.f, 256, SP, part);

  stats2_kernel<<<CCH, 256, 0, stream>>>(part, st);
  bn_kernel<<<(BB * CCH * QQ * NN / 4) / 256, 256, 0, stream>>>(out, st, gq, beta);
}

// Round 8
// 285.879 us; speedup vs baseline: 1.3577x; 1.3577x over previous
//
#include <hip/hip_runtime.h>
#include <math.h>

#define BB 8
#define CCH 256
#define QQ 4
#define NN 1600          // H*W
#define BQN 32           // B*Q
#define SP 51200         // BQN*NN
#define EPSF 1e-5f

typedef __attribute__((ext_vector_type(8))) short bf16x8;  // 8 bf16 (4 VGPRs)
typedef __attribute__((ext_vector_type(4))) float f32x4;

static __device__ inline ushort f2bf(float f) {
  union { float f; unsigned u; } v; v.f = f;
  return (ushort)((v.u + 0x7fffu + ((v.u >> 16) & 1u)) >> 16);  // RNE
}
static __device__ inline float bf2f(ushort u) {
  union { unsigned u; float f; } v; v.u = ((unsigned)u) << 16;
  return v.f;
}
// async 16B global->LDS (lane-linear dest)
static __device__ inline void gld16(const ushort* g, ushort* l) {
  __builtin_amdgcn_global_load_lds(
      (const __attribute__((address_space(1))) unsigned int*)g,
      (__attribute__((address_space(3))) unsigned int*)l, 16, 0, 0);
}

// ---------------- fake-quant weights -> bf16 (wv transposed), gamma, zero r ----------------
__global__ void quant_weights_kernel(const float* Wq, const float* Wk,
                                     const float* Wv, const float* Wp,
                                     const float* gamma,
                                     ushort* wq, ushort* wk, ushort* wvT, ushort* wp,
                                     float* gq, float* r) {
  __shared__ float red[256];
  int blk = blockIdx.x;
  int tid = threadIdx.x;
  if (blk < 1024) {
    int mat = blk >> 8;
    int row = blk & 255;
    const float* W = (mat == 0) ? Wq : (mat == 1) ? Wk : (mat == 2) ? Wv : Wp;
    float w = W[row * 256 + tid];
    red[tid] = fabsf(w);
    __syncthreads();
    for (int s = 128; s > 0; s >>= 1) {
      if (tid < s) red[tid] = fmaxf(red[tid], red[tid + s]);
      __syncthreads();
    }
    float s = red[0] / 127.0f + 1e-8f;
    float q = fminf(fmaxf(rintf(w / s), -127.0f), 127.0f) * s;
    ushort qb = f2bf(q);
    if (mat == 0)      wq[row * 256 + tid] = qb;
    else if (mat == 1) wk[row * 256 + tid] = qb;
    else if (mat == 2) wvT[tid * 256 + row] = qb;   // transposed: wvT[i][d]=Wv[d][i]
    else               wp[row * 256 + tid] = qb;
  } else {
    float g = gamma[tid];
    red[tid] = fabsf(g);
    __syncthreads();
    for (int s = 128; s > 0; s >>= 1) {
      if (tid < s) red[tid] = fmaxf(red[tid], red[tid + s]);
      __syncthreads();
    }
    float s = red[0] / 127.0f + 1e-8f;
    gq[tid] = fminf(fmaxf(rintf(g / s), -127.0f), 127.0f) * s;
    for (int i = tid; i < BQN * 256; i += 256) r[i] = 0.f;  // zero row-sum buf
  }
}

// ---------------- prep: x fp32 -> xb[bq][c][n] bf16 + xT[s][c] bf16 + r row-sums ----------------
__global__ __launch_bounds__(256)
void prep_kernel(const float* __restrict__ x, ushort* __restrict__ xb,
                 ushort* __restrict__ xT, float* __restrict__ r) {
  int bqi = blockIdx.z, b = bqi >> 2, q = bqi & 3;
  int s0 = blockIdx.x * 64, c0 = blockIdx.y * 64;
  __shared__ ushort lT[64 * 66];
  int tid = threadIdx.x;
  int c = tid >> 2, nch = (tid & 3) * 16;
  const float* xp = x + ((size_t)(b * CCH + c0 + c) * QQ + q) * NN + s0 + nch;
  union { ushort u[16]; int4 v[2]; } nb;
  float s = 0.f;
#pragma unroll
  for (int j = 0; j < 4; j++) {
    float4 f = ((const float4*)xp)[j];
    s += f.x + f.y + f.z + f.w;
    nb.u[j * 4 + 0] = f2bf(f.x);
    nb.u[j * 4 + 1] = f2bf(f.y);
    nb.u[j * 4 + 2] = f2bf(f.z);
    nb.u[j * 4 + 3] = f2bf(f.w);
    lT[c * 66 + nch + j * 4 + 0] = nb.u[j * 4 + 0];
    lT[c * 66 + nch + j * 4 + 1] = nb.u[j * 4 + 1];
    lT[c * 66 + nch + j * 4 + 2] = nb.u[j * 4 + 2];
    lT[c * 66 + nch + j * 4 + 3] = nb.u[j * 4 + 3];
  }
  // natural-layout bf16 write
  ushort* xbp = xb + (size_t)bqi * (CCH * NN) + (size_t)(c0 + c) * NN + s0 + nch;
  *(int4*)xbp = nb.v[0];
  *((int4*)xbp + 1) = nb.v[1];
  // row-sum r[bq][c]
  s += __shfl_down(s, 2);
  s += __shfl_down(s, 1);
  if ((tid & 3) == 0) atomicAdd(&r[bqi * 256 + c0 + c], s);
  __syncthreads();
  int n = tid >> 2, cch = (tid & 3) * 16;
  union { ushort u[16]; int4 v[2]; } o;
#pragma unroll
  for (int i = 0; i < 16; i++) o.u[i] = lT[(cch + i) * 66 + n];
  ushort* dst = xT + (size_t)(bqi * NN + s0 + n) * CCH + c0 + cch;
  *(int4*)dst = o.v[0];
  *((int4*)dst + 1) = o.v[1];
}

// ---------------- Gram: G[bq] = Xb Xb^T (M=N=256, K=1600), out split bf16 Gh+Gl ----------------
__global__ __launch_bounds__(256)
void gram_kernel(const ushort* __restrict__ xb, ushort* __restrict__ Gh,
                 ushort* __restrict__ Gl) {
  __shared__ __align__(16) char smem[32768];
  float* lC = (float*)smem;
  int z = blockIdx.z;
  int mBase = blockIdx.y * 128, nBase = blockIdx.x * 128;
  int tid = threadIdx.x, wave = tid >> 6, lane = tid & 63;
  int wm = wave >> 1, wn = wave & 1;
  int col = lane & 15, quad = lane >> 4;
  int srow = tid >> 2, skc = (tid & 3) * 8;
  const ushort* X = xb + (size_t)z * (CCH * NN);
  const ushort* gA  = X + (size_t)(mBase + srow) * NN + skc;
  const ushort* gA2 = gA + (size_t)64 * NN;
  const ushort* gB  = X + (size_t)(nBase + srow) * NN + skc;
  const ushort* gB2 = gB + (size_t)64 * NN;
  ushort* sA1[2]; ushort* sA2[2]; ushort* sB1[2]; ushort* sB2[2];
#pragma unroll
  for (int b = 0; b < 2; b++) {
    ushort* lAb = (ushort*)(smem + b * 16384);
    ushort* lBb = (ushort*)(smem + b * 16384 + 8192);
    sA1[b] = &lAb[srow * 32 + skc];
    sA2[b] = &lAb[(64 + srow) * 32 + skc];
    sB1[b] = &lBb[srow * 32 + skc];
    sB2[b] = &lBb[(64 + srow) * 32 + skc];
  }
  f32x4 acc[4][4];
#pragma unroll
  for (int i = 0; i < 4; i++)
#pragma unroll
    for (int j = 0; j < 4; j++) acc[i][j] = (f32x4){0.f, 0.f, 0.f, 0.f};

  const int nIter = NN / 32;   // 50
  gld16(gA, sA1[0]); gld16(gA2, sA2[0]); gld16(gB, sB1[0]); gld16(gB2, sB2[0]);
  for (int it = 0; it < nIter; ++it) {
    int cur = it & 1;
    __syncthreads();
    if (it + 1 < nIter) {
      int kt = (it + 1) << 5, nxt = cur ^ 1;
      gld16(gA + kt, sA1[nxt]); gld16(gA2 + kt, sA2[nxt]);
      gld16(gB + kt, sB1[nxt]); gld16(gB2 + kt, sB2[nxt]);
    }
    const ushort* lAc = (const ushort*)(smem + cur * 16384);
    const ushort* lBc = (const ushort*)(smem + cur * 16384 + 8192);
    bf16x8 af[4], bfr[4];
#pragma unroll
    for (int i = 0; i < 4; i++)
      af[i] = *(const bf16x8*)&lAc[(wm * 64 + i * 16 + col) * 32 + quad * 8];
#pragma unroll
    for (int j = 0; j < 4; j++)
      bfr[j] = *(const bf16x8*)&lBc[(wn * 64 + j * 16 + col) * 32 + quad * 8];
#pragma unroll
    for (int i = 0; i < 4; i++)
#pragma unroll
      for (int j = 0; j < 4; j++)
        acc[i][j] = __builtin_amdgcn_mfma_f32_16x16x32_bf16(af[i], bfr[j], acc[i][j], 0, 0, 0);
  }
  __syncthreads();
  float* lCw = lC + wave * 16 * 68;
  int mW = mBase + wm * 64, nW = nBase + wn * 64;
#pragma unroll
  for (int i = 0; i < 4; i++) {
#pragma unroll
    for (int j = 0; j < 4; j++)
#pragma unroll
      for (int rg = 0; rg < 4; rg++)
        lCw[(quad * 4 + rg) * 68 + j * 16 + col] = acc[i][j][rg];
    int mrow0 = mW + i * 16;
    int rr = lane & 15, cc = lane >> 4;
    union { ushort u[16]; int4 v[2]; } oh, ol;
#pragma unroll
    for (int t = 0; t < 16; t++) {
      float vfl = lCw[rr * 68 + cc * 16 + t];
      ushort hh = f2bf(vfl);
      oh.u[t] = hh;
      ol.u[t] = f2bf(vfl - bf2f(hh));
    }
    size_t off = (size_t)z * 65536 + (size_t)(mrow0 + rr) * 256 + nW + cc * 16;
    *(int4*)(Gh + off) = oh.v[0];
    *((int4*)(Gh + off) + 1) = oh.v[1];
    *(int4*)(Gl + off) = ol.v[0];
    *((int4*)(Gl + off) + 1) = ol.v[1];
  }
}

// ---------------- small 256x256x256 GEMMs: C = A * B^T (per z) ----------------
// MODE 0: M1 = wq * (Gh+Gl)^T  -> dual bf16 [m][n] (M1h, M1l)
// MODE 1: S  = (M1h+M1l) * wk^T -> fp32 [m][n]
// MODE 2: N1 = P * wvT^T        -> bf16 transposed [n][m]
// MODE 3: T  = wp * N1^T        -> bf16 [m][n]
template<int MODE>
__global__ __launch_bounds__(256)
void gemm256(const ushort* __restrict__ A, long sA, const ushort* __restrict__ A2,
             const ushort* __restrict__ B, long sB, const ushort* __restrict__ B2,
             void* __restrict__ C1, void* __restrict__ C2, long sC) {
  __shared__ __align__(16) char smem[24576];
  ushort* lA = (ushort*)smem;
  ushort* lB = (ushort*)(smem + 8192);
  ushort* lX = (ushort*)(smem + 16384);
  float* lC = (float*)smem;
  int z = blockIdx.z;
  int mBase = blockIdx.y * 128, nBase = blockIdx.x * 128;
  int tid = threadIdx.x, wave = tid >> 6, lane = tid & 63;
  int wm = wave >> 1, wn = wave & 1;
  int col = lane & 15, quad = lane >> 4;
  int srow = tid >> 2, skc = (tid & 3) * 8;
  const ushort* Az = A + (size_t)z * sA;
  const ushort* Bz = B + (size_t)z * sB;
  const ushort* gA  = Az + (size_t)(mBase + srow) * 256 + skc;
  const ushort* gA2r = gA + 64 * 256;
  const ushort* gB  = Bz + (size_t)(nBase + srow) * 256 + skc;
  const ushort* gB2r = gB + 64 * 256;
  const ushort* gX = nullptr;
  const ushort* gX2 = nullptr;
  if (MODE == 0) {
    const ushort* Xz = B2 + (size_t)z * sB;
    gX = Xz + (size_t)(nBase + srow) * 256 + skc;
    gX2 = gX + 64 * 256;
  } else if (MODE == 1) {
    const ushort* Xz = A2 + (size_t)z * sA;
    gX = Xz + (size_t)(mBase + srow) * 256 + skc;
    gX2 = gX + 64 * 256;
  }
  ushort* dA1 = &lA[srow * 32 + skc]; ushort* dA2 = &lA[(64 + srow) * 32 + skc];
  ushort* dB1 = &lB[srow * 32 + skc]; ushort* dB2 = &lB[(64 + srow) * 32 + skc];
  ushort* dX1 = &lX[srow * 32 + skc]; ushort* dX2 = &lX[(64 + srow) * 32 + skc];

  f32x4 acc[4][4];
#pragma unroll
  for (int i = 0; i < 4; i++)
#pragma unroll
    for (int j = 0; j < 4; j++) acc[i][j] = (f32x4){0.f, 0.f, 0.f, 0.f};

  for (int kt = 0; kt < 256; kt += 32) {
    __syncthreads();
    gld16(gA + kt, dA1); gld16(gA2r + kt, dA2);
    gld16(gB + kt, dB1); gld16(gB2r + kt, dB2);
    if (MODE <= 1) { gld16(gX + kt, dX1); gld16(gX2 + kt, dX2); }
    __syncthreads();
    bf16x8 af[4], bfr[4], xf[4];
#pragma unroll
    for (int i = 0; i < 4; i++)
      af[i] = *(const bf16x8*)&lA[(wm * 64 + i * 16 + col) * 32 + quad * 8];
#pragma unroll
    for (int j = 0; j < 4; j++)
      bfr[j] = *(const bf16x8*)&lB[(wn * 64 + j * 16 + col) * 32 + quad * 8];
    if (MODE == 0) {
#pragma unroll
      for (int j = 0; j < 4; j++)
        xf[j] = *(const bf16x8*)&lX[(wn * 64 + j * 16 + col) * 32 + quad * 8];
    } else if (MODE == 1) {
#pragma unroll
      for (int i = 0; i < 4; i++)
        xf[i] = *(const bf16x8*)&lX[(wm * 64 + i * 16 + col) * 32 + quad * 8];
    }
#pragma unroll
    for (int i = 0; i < 4; i++)
#pragma unroll
      for (int j = 0; j < 4; j++) {
        acc[i][j] = __builtin_amdgcn_mfma_f32_16x16x32_bf16(af[i], bfr[j], acc[i][j], 0, 0, 0);
        if (MODE == 0)
          acc[i][j] = __builtin_amdgcn_mfma_f32_16x16x32_bf16(af[i], xf[j], acc[i][j], 0, 0, 0);
        else if (MODE == 1)
          acc[i][j] = __builtin_amdgcn_mfma_f32_16x16x32_bf16(xf[i], bfr[j], acc[i][j], 0, 0, 0);
      }
  }
  __syncthreads();
  float* lCw = lC + wave * 16 * 68;
  int mW = mBase + wm * 64, nW = nBase + wn * 64;
#pragma unroll
  for (int i = 0; i < 4; i++) {
#pragma unroll
    for (int j = 0; j < 4; j++)
#pragma unroll
      for (int rg = 0; rg < 4; rg++)
        lCw[(quad * 4 + rg) * 68 + j * 16 + col] = acc[i][j][rg];
    int mrow0 = mW + i * 16;
    int rr = lane & 15, cc = lane >> 4;
    if (MODE == 0) {
      union { ushort u[16]; int4 v[2]; } oh, ol;
#pragma unroll
      for (int t = 0; t < 16; t++) {
        float vfl = lCw[rr * 68 + cc * 16 + t];
        ushort hh = f2bf(vfl);
        oh.u[t] = hh;
        ol.u[t] = f2bf(vfl - bf2f(hh));
      }
      size_t off = (size_t)z * sC + (size_t)(mrow0 + rr) * 256 + nW + cc * 16;
      *(int4*)((ushort*)C1 + off) = oh.v[0];
      *((int4*)((ushort*)C1 + off) + 1) = oh.v[1];
      *(int4*)((ushort*)C2 + off) = ol.v[0];
      *((int4*)((ushort*)C2 + off) + 1) = ol.v[1];
    } else if (MODE == 1) {
      float* C = (float*)C1 + (size_t)z * sC + (size_t)(mrow0 + rr) * 256 + nW + cc * 16;
#pragma unroll
      for (int v = 0; v < 4; v++) {
        float4 f;
        f.x = lCw[rr * 68 + cc * 16 + v * 4 + 0];
        f.y = lCw[rr * 68 + cc * 16 + v * 4 + 1];
        f.z = lCw[rr * 68 + cc * 16 + v * 4 + 2];
        f.w = lCw[rr * 68 + cc * 16 + v * 4 + 3];
        *(float4*)(C + v * 4) = f;
      }
    } else if (MODE == 2) {
      int n = nW + lane;
      union { ushort u[16]; int4 v[2]; } o;
#pragma unroll
      for (int t = 0; t < 16; t++) o.u[t] = f2bf(lCw[t * 68 + lane]);
      ushort* C = (ushort*)C1 + (size_t)z * sC + (size_t)n * 256 + mrow0;
      *(int4*)C = o.v[0];
      *((int4*)C + 1) = o.v[1];
    } else {
      union { ushort u[16]; int4 v[2]; } o;
#pragma unroll
      for (int t = 0; t < 16; t++) o.u[t] = f2bf(lCw[rr * 68 + cc * 16 + t]);
      ushort* C = (ushort*)C1 + (size_t)z * sC + (size_t)(mrow0 + rr) * 256 + nW + cc * 16;
      *(int4*)C = o.v[0];
      *((int4*)C + 1) = o.v[1];
    }
  }
}

// ---------------- u = Wq*r, v = Wk*r (bias rank-1 helpers) ----------------
__global__ void uv_kernel(const ushort* __restrict__ wq, const ushort* __restrict__ wk,
                          const float* __restrict__ r, float* __restrict__ u,
                          float* __restrict__ vv) {
  int bq = blockIdx.x, sel = blockIdx.y, c = threadIdx.x;
  const ushort* W = sel ? wk : wq;
  float s = 0.f;
  for (int i = 0; i < 256; i++) s += bf2f(W[c * 256 + i]) * r[bq * 256 + i];
  (sel ? vv : u)[bq * 256 + c] = s;
}

// ---------------- softmax with bias rank-1 terms; emits P bf16 + pb = P.bv ----------------
__global__ void softmax_kernel(const float* __restrict__ S, const float* __restrict__ u,
                               const float* __restrict__ vv, const float* __restrict__ bqv,
                               const float* __restrict__ bkv, const float* __restrict__ bvv,
                               ushort* __restrict__ P, float* __restrict__ pb) {
  int bi = blockIdx.x;
  int bq = bi >> 8, rw = bi & 255;
  int tid = threadIdx.x;
  size_t off = (size_t)bq * 65536 + (size_t)rw * 256 + tid;
  float bqc = bqv[rw], bkd = bkv[tid];
  float val = 0.125f * (S[off] + u[bq * 256 + rw] * bkd + bqc * vv[bq * 256 + tid]
                        + 1600.0f * bqc * bkd);
  __shared__ float red[256];
  red[tid] = val;
  __syncthreads();
  for (int s = 128; s > 0; s >>= 1) {
    if (tid < s) red[tid] = fmaxf(red[tid], red[tid + s]);
    __syncthreads();
  }
  float m = red[0];
  __syncthreads();
  float e = expf(val - m);
  red[tid] = e;
  __syncthreads();
  for (int s = 128; s > 0; s >>= 1) {
    if (tid < s) red[tid] += red[tid + s];
    __syncthreads();
  }
  float p = e / red[0];
  P[off] = f2bf(p);
  __syncthreads();
  red[tid] = p * bvv[tid];
  __syncthreads();
  for (int s = 128; s > 0; s >>= 1) {
    if (tid < s) red[tid] += red[tid + s];
    __syncthreads();
  }
  if (tid == 0) pb[bq * 256 + rw] = red[0];
}

// ---------------- bo[bq][o] = Wp*pb + bp ----------------
__global__ void bo_kernel(const ushort* __restrict__ wp, const float* __restrict__ pb,
                          const float* __restrict__ bp, float* __restrict__ bo) {
  int bq = blockIdx.x, o = threadIdx.x;
  float s = bp[o];
  for (int c = 0; c < 256; c++) s += bf2f(wp[o * 256 + c]) * pb[bq * 256 + c];
  bo[bq * 256 + o] = s;
}

// ---------------- final: out[b][o][q][:] = T[bq] * X[bq] + bo, fused stats ----------------
__global__ __launch_bounds__(256)
void final_kernel(const ushort* __restrict__ Tm, const ushort* __restrict__ xT,
                  const float* __restrict__ bo, float* __restrict__ out,
                  float* __restrict__ part) {
  __shared__ __align__(16) char smem[32768];
  float* lC = (float*)smem;
  __shared__ float psS[2][128];
  __shared__ float psS2[2][128];
  int z = blockIdx.z;
  int mBase = blockIdx.y * 128, nBase = blockIdx.x * 128;
  int tid = threadIdx.x, wave = tid >> 6, lane = tid & 63;
  int wm = wave >> 1, wn = wave & 1;
  int col = lane & 15, quad = lane >> 4;
  int srow = tid >> 2, skc = (tid & 3) * 8;
  const ushort* Az = Tm + (size_t)z * 65536;
  const ushort* Bz = xT + (size_t)z * (NN * 256);
  const ushort* gA  = Az + (size_t)(mBase + srow) * 256 + skc;
  const ushort* gA2 = gA + 64 * 256;
  int br1 = nBase + srow;      br1 = br1 < NN ? br1 : NN - 1;
  int br2 = nBase + 64 + srow; br2 = br2 < NN ? br2 : NN - 1;
  const ushort* gB  = Bz + (size_t)br1 * 256 + skc;
  const ushort* gB2 = Bz + (size_t)br2 * 256 + skc;
  ushort* sA1[2]; ushort* sA2[2]; ushort* sB1[2]; ushort* sB2[2];
#pragma unroll
  for (int b = 0; b < 2; b++) {
    ushort* lAb = (ushort*)(smem + b * 16384);
    ushort* lBb = (ushort*)(smem + b * 16384 + 8192);
    sA1[b] = &lAb[srow * 32 + skc];
    sA2[b] = &lAb[(64 + srow) * 32 + skc];
    sB1[b] = &lBb[srow * 32 + skc];
    sB2[b] = &lBb[(64 + srow) * 32 + skc];
  }
  f32x4 acc[4][4];
#pragma unroll
  for (int i = 0; i < 4; i++)
#pragma unroll
    for (int j = 0; j < 4; j++) acc[i][j] = (f32x4){0.f, 0.f, 0.f, 0.f};

  const int nIter = 8;  // K=256
  gld16(gA, sA1[0]); gld16(gA2, sA2[0]); gld16(gB, sB1[0]); gld16(gB2, sB2[0]);
  for (int it = 0; it < nIter; ++it) {
    int cur = it & 1;
    __syncthreads();
    if (it + 1 < nIter) {
      int kt = (it + 1) << 5, nxt = cur ^ 1;
      gld16(gA + kt, sA1[nxt]); gld16(gA2 + kt, sA2[nxt]);
      gld16(gB + kt, sB1[nxt]); gld16(gB2 + kt, sB2[nxt]);
    }
    const ushort* lAc = (const ushort*)(smem + cur * 16384);
    const ushort* lBc = (const ushort*)(smem + cur * 16384 + 8192);
    bf16x8 af[4], bfr[4];
#pragma unroll
    for (int i = 0; i < 4; i++)
      af[i] = *(const bf16x8*)&lAc[(wm * 64 + i * 16 + col) * 32 + quad * 8];
#pragma unroll
    for (int j = 0; j < 4; j++)
      bfr[j] = *(const bf16x8*)&lBc[(wn * 64 + j * 16 + col) * 32 + quad * 8];
#pragma unroll
    for (int i = 0; i < 4; i++)
#pragma unroll
      for (int j = 0; j < 4; j++)
        acc[i][j] = __builtin_amdgcn_mfma_f32_16x16x32_bf16(af[i], bfr[j], acc[i][j], 0, 0, 0);
  }
  __syncthreads();
  float* lCw = lC + wave * 16 * 68;
  int mW = mBase + wm * 64, nW = nBase + wn * 64;
  int b = z >> 2, q = z & 3;
#pragma unroll
  for (int i = 0; i < 4; i++) {
#pragma unroll
    for (int j = 0; j < 4; j++)
#pragma unroll
      for (int rg = 0; rg < 4; rg++)
        lCw[(quad * 4 + rg) * 68 + j * 16 + col] = acc[i][j][rg];
    int mrow0 = mW + i * 16;
    int rr = lane & 15, cc = lane >> 4;
    int n0 = nW + cc * 16;
    float bi = bo[(size_t)z * 256 + mrow0 + rr];
    float ls = 0.f, ls2 = 0.f;
    if (n0 < NN) {
      float* C = out + (size_t)b * (CCH * QQ * NN)
               + (size_t)(mrow0 + rr) * (QQ * NN) + (size_t)q * NN + n0;
#pragma unroll
      for (int v = 0; v < 4; v++) {
        float4 f;
        f.x = lCw[rr * 68 + cc * 16 + v * 4 + 0] + bi;
        f.y = lCw[rr * 68 + cc * 16 + v * 4 + 1] + bi;
        f.z = lCw[rr * 68 + cc * 16 + v * 4 + 2] + bi;
        f.w = lCw[rr * 68 + cc * 16 + v * 4 + 3] + bi;
        *(float4*)(C + v * 4) = f;
        ls  += f.x + f.y + f.z + f.w;
        ls2 += f.x * f.x + f.y * f.y + f.z * f.z + f.w * f.w;
      }
    }
    ls  += __shfl_down(ls, 32);  ls  += __shfl_down(ls, 16);
    ls2 += __shfl_down(ls2, 32); ls2 += __shfl_down(ls2, 16);
    if (lane < 16) {
      psS[wn][wm * 64 + i * 16 + lane] = ls;
      psS2[wn][wm * 64 + i * 16 + lane] = ls2;
    }
  }
  __syncthreads();
  if (tid < 128) {
    float s  = psS[0][tid] + psS[1][tid];
    float s2 = psS2[0][tid] + psS2[1][tid];
    int slot = z * 13 + blockIdx.x;
    part[(size_t)slot * 256 + mBase + tid] = s;
    part[416 * 256 + (size_t)slot * 256 + mBase + tid] = s2;
  }
}

// ---------------- stats finalize: reduce 416 partial slots per channel ----------------
__global__ void stats2_kernel(const float* __restrict__ part, float* __restrict__ st) {
  int o = blockIdx.x;
  int tid = threadIdx.x;
  float s = 0.f, s2 = 0.f;
  for (int x = tid; x < 416; x += 256) {
    s  += part[(size_t)x * 256 + o];
    s2 += part[416 * 256 + (size_t)x * 256 + o];
  }
  __shared__ float rs[256], rs2[256];
  rs[tid] = s; rs2[tid] = s2;
  __syncthreads();
  for (int t = 128; t > 0; t >>= 1) {
    if (tid < t) { rs[tid] += rs[tid + t]; rs2[tid] += rs2[tid + t]; }
    __syncthreads();
  }
  if (tid == 0) {
    float inv = 1.0f / (float)(BQN * NN);
    float mean = rs[0] * inv;
    float var = rs2[0] * inv - mean * mean;
    st[o] = mean;
    st[CCH + o] = var;
  }
}

// ---------------- batch-norm apply (float4) ----------------
__global__ __launch_bounds__(256)
void bn_kernel(float* __restrict__ out, const float* __restrict__ st,
               const float* __restrict__ gq, const float* __restrict__ beta) {
  size_t i4 = (size_t)blockIdx.x * 256 + threadIdx.x;  // 3276800 float4s exactly
  int o = (int)((i4 / 1600) & 255);
  float mean = st[o];
  float g = rsqrtf(st[CCH + o] + EPSF) * gq[o];
  float be = beta[o];
  float4 f = ((const float4*)out)[i4];
  f.x = (f.x - mean) * g + be;
  f.y = (f.y - mean) * g + be;
  f.z = (f.z - mean) * g + be;
  f.w = (f.w - mean) * g + be;
  ((float4*)out)[i4] = f;
}

extern "C" void kernel_launch(void* const* d_in, const int* in_sizes, int n_in,
                              void* d_out, int out_size, void* d_ws, size_t ws_size,
                              hipStream_t stream) {
  const float* x     = (const float*)d_in[0];
  const float* Wq    = (const float*)d_in[1];
  const float* bq    = (const float*)d_in[2];
  const float* Wk    = (const float*)d_in[3];
  const float* bk    = (const float*)d_in[4];
  const float* Wv    = (const float*)d_in[5];
  const float* bv    = (const float*)d_in[6];
  const float* Wp    = (const float*)d_in[7];
  const float* bp    = (const float*)d_in[8];
  const float* gamma = (const float*)d_in[9];
  const float* beta  = (const float*)d_in[10];
  float* out = (float*)d_out;

  ushort* h    = (ushort*)d_ws;
  ushort* wq   = h;                      // 65536 each
  ushort* wk   = wq + 65536;
  ushort* wp   = wk + 65536;
  ushort* wvT  = wp + 65536;
  ushort* xb   = wvT + 65536;            // [32][256][1600]
  ushort* xT   = xb + (size_t)BQN * CCH * NN;   // [51200][256]
  ushort* Gh   = xT + (size_t)BQN * CCH * NN;   // [32][256][256]
  ushort* Gl   = Gh + (size_t)BQN * 65536;
  ushort* M1h  = Gl + (size_t)BQN * 65536;
  ushort* M1l  = M1h + (size_t)BQN * 65536;
  ushort* P    = M1l + (size_t)BQN * 65536;
  ushort* N1t  = P + (size_t)BQN * 65536;
  ushort* Tm   = N1t + (size_t)BQN * 65536;
  float*  S    = (float*)(Tm + (size_t)BQN * 65536);   // [32][256][256] fp32
  float*  r    = S + (size_t)BQN * 65536;  // 8192
  float*  u    = r + 8192;
  float*  vv   = u + 8192;
  float*  pb   = vv + 8192;
  float*  bo   = pb + 8192;
  float*  gq   = bo + 8192;              // 256
  float*  st   = gq + 256;               // 512
  float*  part = st + 512;               // 2*416*256

  quant_weights_kernel<<<1025, 256, 0, stream>>>(Wq, Wk, Wv, Wp, gamma,
                                                 wq, wk, wvT, wp, gq, r);
  prep_kernel<<<dim3(NN / 64, CCH / 64, BQN), 256, 0, stream>>>(x, xb, xT, r);
  uv_kernel<<<dim3(BQN, 2), 256, 0, stream>>>(wq, wk, r, u, vv);
  // G = Xb Xb^T per bq (K=1600), split bf16 out
  gram_kernel<<<dim3(2, 2, BQN), 256, 0, stream>>>(xb, Gh, Gl);
  // M1 = wq * G (G symmetric, split B)
  gemm256<0><<<dim3(2, 2, BQN), 256, 0, stream>>>(
      wq, 0, nullptr, Gh, 65536, Gl, M1h, M1l, 65536);
  // S = M1 * wk^T (split A)
  gemm256<1><<<dim3(2, 2, BQN), 256, 0, stream>>>(
      M1h, 65536, M1l, wk, 0, nullptr, S, nullptr, 65536);
  softmax_kernel<<<BQN * CCH, 256, 0, stream>>>(S, u, vv, bq, bk, bv, P, pb);
  // N1t = (P * wvT^T)^T
  gemm256<2><<<dim3(2, 2, BQN), 256, 0, stream>>>(
      P, 65536, nullptr, wvT, 0, nullptr, N1t, nullptr, 65536);
  // T = wp * N1t^T
  gemm256<3><<<dim3(2, 2, BQN), 256, 0, stream>>>(
      wp, 0, nullptr, N1t, 65536, nullptr, Tm, nullptr, 65536);
  bo_kernel<<<BQN, 256, 0, stream>>>(wp, pb, bp, bo);
  // out = T * X^T + bo, fused stats partials
  final_kernel<<<dim3(13, 2, BQN), 256, 0, stream>>>(Tm, xT, bo, out, part);
  stats2_kernel<<<CCH, 256, 0, stream>>>(part, st);
  bn_kernel<<<(BB * CCH * QQ * NN / 4) / 256, 256, 0, stream>>>(out, st, gq, beta);
}